// Round 1
// baseline (456.833 us; speedup 1.0000x reference)
//
#include <hip/hip_runtime.h>
#include <hip/hip_bf16.h>
#include <math.h>

// Problem constants (fixed by setup_inputs)
constexpr int NQ = 22500;       // 150*150
constexpr int GH = 150, GW = 150;
constexpr int EMBED = 256;
constexpr int NHEAD = 8;
constexpr int HDIM = 32;

// ---------------------------------------------------------------------------
// Generic register-tiled f32 GEMM:  C[M,N] = A[M,K] @ B[K,N] + bias (+ ident)
// QCAT: A element (m,k) = k<256 ? query[m,k] : query[m,k-256]+query_pos[m,k-256]
// ---------------------------------------------------------------------------
template <bool QCAT, bool ADD_ID>
__global__ __launch_bounds__(256) void gemm_f32_kernel(
    const float* __restrict__ A, const float* __restrict__ A2,
    const float* __restrict__ B, const float* __restrict__ bias,
    const float* __restrict__ ident, float* __restrict__ C,
    int M, int N, int K)
{
    constexpr int BM = 64, BN = 64, BK = 16;
    __shared__ float As[BK][BM + 1];
    __shared__ float Bs[BK][BN + 1];

    const int tid = threadIdx.x;
    const int block_row = blockIdx.x * BM;
    const int block_col = blockIdx.y * BN;
    const int tx = tid & 15;   // 0..15 -> cols
    const int ty = tid >> 4;   // 0..15 -> rows

    float acc[4][4] = {};

    for (int k0 = 0; k0 < K; k0 += BK) {
        // Load A tile (BM x BK = 1024 elems, 4 per thread)
#pragma unroll
        for (int i = 0; i < 4; ++i) {
            int idx = tid + i * 256;       // 0..1023
            int ar = idx >> 4;             // /BK : 0..63
            int ac = idx & 15;             // %BK
            int gr = block_row + ar;
            int gk = k0 + ac;
            float v = 0.f;
            if (gr < M) {
                if (!QCAT) {
                    v = A[gr * K + gk];
                } else {
                    if (gk < EMBED) v = A[gr * EMBED + gk];
                    else            v = A[gr * EMBED + gk - EMBED] + A2[gr * EMBED + gk - EMBED];
                }
            }
            As[ac][ar] = v;
        }
        // Load B tile (BK x BN = 1024 elems)
#pragma unroll
        for (int i = 0; i < 4; ++i) {
            int idx = tid + i * 256;
            int br = idx >> 6;             // /BN : 0..15
            int bc = idx & 63;             // %BN
            Bs[br][bc] = B[(k0 + br) * N + block_col + bc];
        }
        __syncthreads();

#pragma unroll
        for (int k = 0; k < BK; ++k) {
            float a[4], b[4];
#pragma unroll
            for (int i = 0; i < 4; ++i) a[i] = As[k][ty * 4 + i];
#pragma unroll
            for (int j = 0; j < 4; ++j) b[j] = Bs[k][tx * 4 + j];
#pragma unroll
            for (int i = 0; i < 4; ++i)
#pragma unroll
                for (int j = 0; j < 4; ++j) acc[i][j] += a[i] * b[j];
        }
        __syncthreads();
    }

#pragma unroll
    for (int i = 0; i < 4; ++i) {
        int gr = block_row + ty * 4 + i;
        if (gr >= M) continue;
#pragma unroll
        for (int j = 0; j < 4; ++j) {
            int gc = block_col + tx * 4 + j;
            float v = acc[i][j] + bias[gc];
            if (ADD_ID) v += ident[gr * N + gc];
            C[gr * N + gc] = v;
        }
    }
}

// ---------------------------------------------------------------------------
// Deformable sampling + softmax + queue-mean.
// Block = 256 threads = 8 groups of 32 lanes. Group g handles head h=g of
// query q=blockIdx.x; lane d = channel within head.
// ---------------------------------------------------------------------------
__global__ __launch_bounds__(256) void msda_kernel(
    const float* __restrict__ value,   // (NQ, 8, 32)
    const float* __restrict__ refpts,  // (2, NQ, 1, 2)
    const float* __restrict__ off,     // (NQ, 128)  = (h, j, p, 2)
    const float* __restrict__ attn,    // (NQ, 64)   = (h, j, p)
    float* __restrict__ out)           // (NQ, 256)
{
    const int q = blockIdx.x;
    const int h = threadIdx.x >> 5;
    const int d = threadIdx.x & 31;

    float acc = 0.f;

#pragma unroll
    for (int j = 0; j < 2; ++j) {
        const float rx = refpts[(j * NQ + q) * 2 + 0];
        const float ry = refpts[(j * NQ + q) * 2 + 1];

        // softmax over the 4 points (redundant per-lane, tiny)
        float a[4];
        float m = -1e30f;
#pragma unroll
        for (int p = 0; p < 4; ++p) {
            a[p] = attn[q * 64 + h * 8 + j * 4 + p];
            m = fmaxf(m, a[p]);
        }
        float s = 0.f;
#pragma unroll
        for (int p = 0; p < 4; ++p) { a[p] = expf(a[p] - m); s += a[p]; }
        const float inv = 1.f / s;

#pragma unroll
        for (int p = 0; p < 4; ++p) {
            const float ox = off[q * 128 + h * 16 + j * 8 + p * 2 + 0];
            const float oy = off[q * 128 + h * 16 + j * 8 + p * 2 + 1];
            // loc = ref + off/normalizer; x = loc_x*W - 0.5
            const float x = (rx + ox * (1.f / 150.f)) * 150.f - 0.5f;
            const float y = (ry + oy * (1.f / 150.f)) * 150.f - 0.5f;
            const float x0f = floorf(x), y0f = floorf(y);
            const float wx1 = x - x0f, wy1 = y - y0f;
            const int x0 = (int)x0f, y0 = (int)y0f;
            const float aw = a[p] * inv;

#pragma unroll
            for (int cy = 0; cy < 2; ++cy) {
#pragma unroll
                for (int cx = 0; cx < 2; ++cx) {
                    const int ix = x0 + cx;
                    const int iy = y0 + cy;
                    if (ix >= 0 && ix < GW && iy >= 0 && iy < GH) {
                        const float w = (cx ? wx1 : 1.f - wx1) * (cy ? wy1 : 1.f - wy1);
                        acc += aw * w * value[(iy * GW + ix) * EMBED + h * HDIM + d];
                    }
                }
            }
        }
    }

    out[q * EMBED + h * HDIM + d] = 0.5f * acc;
}

// ---------------------------------------------------------------------------
extern "C" void kernel_launch(void* const* d_in, const int* in_sizes, int n_in,
                              void* d_out, int out_size, void* d_ws, size_t ws_size,
                              hipStream_t stream)
{
    const float* query     = (const float*)d_in[0];   // (1, NQ, 256)
    const float* query_pos = (const float*)d_in[1];   // (1, NQ, 256)
    const float* refpts    = (const float*)d_in[2];   // (2, NQ, 1, 2)
    const float* W_off     = (const float*)d_in[3];   // (512, 128)
    const float* b_off     = (const float*)d_in[4];   // (128)
    const float* W_attn    = (const float*)d_in[5];   // (512, 64)
    const float* b_attn    = (const float*)d_in[6];   // (64)
    const float* W_v       = (const float*)d_in[7];   // (256, 256)
    const float* b_v       = (const float*)d_in[8];   // (256)
    const float* W_out     = (const float*)d_in[9];   // (256, 256)
    const float* b_out     = (const float*)d_in[10];  // (256)
    float* out             = (float*)d_out;           // (1, NQ, 256)

    // Workspace carve-up (f32):
    float* ws      = (float*)d_ws;
    float* value   = ws;                       // NQ*256
    float* off_b   = value + (size_t)NQ * 256; // NQ*128
    float* attn_b  = off_b + (size_t)NQ * 128; // NQ*64
    float* msda    = attn_b + (size_t)NQ * 64; // NQ*256

    const int mblocks = (NQ + 63) / 64;

    // 1. value = query @ W_v + b_v
    gemm_f32_kernel<false, false><<<dim3(mblocks, 4), 256, 0, stream>>>(
        query, nullptr, W_v, b_v, nullptr, value, NQ, 256, 256);

    // 2. off = q_cat @ W_off + b_off   (K=512)
    gemm_f32_kernel<true, false><<<dim3(mblocks, 2), 256, 0, stream>>>(
        query, query_pos, W_off, b_off, nullptr, off_b, NQ, 128, 512);

    // 3. attn_logits = q_cat @ W_attn + b_attn
    gemm_f32_kernel<true, false><<<dim3(mblocks, 1), 256, 0, stream>>>(
        query, query_pos, W_attn, b_attn, nullptr, attn_b, NQ, 64, 512);

    // 4. deformable sampling + softmax + queue mean
    msda_kernel<<<NQ, 256, 0, stream>>>(value, refpts, off_b, attn_b, msda);

    // 5. out = msda @ W_out + b_out + query (identity)
    gemm_f32_kernel<false, true><<<dim3(mblocks, 4), 256, 0, stream>>>(
        msda, nullptr, W_out, b_out, query, out, NQ, 256, 256);
}

// Round 2
// 117.145 us; speedup vs baseline: 3.8997x; 3.8997x over previous
//
#include <hip/hip_runtime.h>
#include <hip/hip_bf16.h>
#include <math.h>

constexpr int NQ   = 22500;      // 150*150
constexpr int NQP  = 22528;      // padded to 176*128
constexpr int GH   = 150, GW = 150;
constexpr int EMBED = 256;

using f32x4 = __attribute__((ext_vector_type(4))) float;
using s16x8 = __attribute__((ext_vector_type(8))) short;

__device__ inline ushort f2bf(float f) {
    __hip_bfloat16 h = __float2bfloat16(f);
    return *reinterpret_cast<ushort*>(&h);
}
__device__ inline float bf2f(uint u) {
    uint x = (u & 0xffffu) << 16;
    return __builtin_bit_cast(float, x);
}

__device__ inline void gload_lds16(const void* g, void* l) {
    __builtin_amdgcn_global_load_lds(
        (const __attribute__((address_space(1))) void*)g,
        (__attribute__((address_space(3))) void*)l, 16, 0, 0);
}

// ---------------------------------------------------------------------------
// bf16 MFMA GEMM: C[M,N] = A[M,K](bf16,row-major,lda) @ Bt[N,K](bf16)^T
//                 + bias (+ identity if OUT_MODE==1)
// OUT_MODE 0: store bf16 (ldc), 1: store f32 + identity
// Tile: BM=128, BN=64, BK=32; 256 threads = 4 waves in 2x2.
// ---------------------------------------------------------------------------
template <int OUT_MODE>
__global__ __launch_bounds__(256) void gemm_bf16_kernel(
    const ushort* __restrict__ A, int lda,
    const ushort* __restrict__ Bt,
    const float* __restrict__ bias,
    const float* __restrict__ ident,
    void* __restrict__ Cout, int ldc,
    int M, int N, int K)
{
    constexpr int BM = 128, BN = 64, BK = 32;
    __shared__ ushort As[BM * BK];   // [row][k], 64B per row
    __shared__ ushort Bs[BN * BK];   // [col][k]

    const int tid  = threadIdx.x;
    const int lane = tid & 63;
    const int w    = tid >> 6;
    const int wm   = w >> 1, wn = w & 1;
    const int l15  = lane & 15, l4 = lane >> 4;
    const int brow = blockIdx.x * BM;
    const int bcol = blockIdx.y * BN;

    f32x4 acc[4][2] = {};

    for (int k0 = 0; k0 < K; k0 += BK) {
        // Stage A: 128x32 bf16 = 8KB = 2 chunks of (256 lanes x 16B)
#pragma unroll
        for (int c = 0; c < 2; ++c) {
            const int idx = c * 256 + tid;                 // linear 16B chunk id
            const ushort* src = A + (size_t)(brow + (idx >> 2)) * lda + k0 + (idx & 3) * 8;
            gload_lds16(src, (char*)As + (c * 256 + w * 64) * 16);
        }
        // Stage B: 64x32 bf16 = 4KB = 1 chunk
        {
            const int idx = tid;
            const ushort* src = Bt + (size_t)(bcol + (idx >> 2)) * K + k0 + (idx & 3) * 8;
            gload_lds16(src, (char*)Bs + (w * 64) * 16);
        }
        __syncthreads();

        s16x8 a[4], b[2];
#pragma unroll
        for (int mi = 0; mi < 4; ++mi)
            a[mi] = *(const s16x8*)&As[(wm * 64 + mi * 16 + l15) * BK + l4 * 8];
#pragma unroll
        for (int ni = 0; ni < 2; ++ni)
            b[ni] = *(const s16x8*)&Bs[(wn * 32 + ni * 16 + l15) * BK + l4 * 8];
#pragma unroll
        for (int mi = 0; mi < 4; ++mi)
#pragma unroll
            for (int ni = 0; ni < 2; ++ni)
                acc[mi][ni] = __builtin_amdgcn_mfma_f32_16x16x32_bf16(
                    a[mi], b[ni], acc[mi][ni], 0, 0, 0);
        __syncthreads();
    }

    // Epilogue: C/D layout col=lane&15, row=(lane>>4)*4+r
#pragma unroll
    for (int mi = 0; mi < 4; ++mi) {
#pragma unroll
        for (int r = 0; r < 4; ++r) {
            const int gr = brow + wm * 64 + mi * 16 + l4 * 4 + r;
            if (gr >= M) continue;
#pragma unroll
            for (int ni = 0; ni < 2; ++ni) {
                const int gc = bcol + wn * 32 + ni * 16 + l15;
                float v = acc[mi][ni][r] + bias[gc];
                if (OUT_MODE == 1) {
                    v += ident[(size_t)gr * ldc + gc];
                    ((float*)Cout)[(size_t)gr * ldc + gc] = v;
                } else {
                    ((ushort*)Cout)[(size_t)gr * ldc + gc] = f2bf(v);
                }
            }
        }
    }
}

// ---------------------------------------------------------------------------
// Build q_cat bf16: row q = [query | query+query_pos], NQ x 512
// ---------------------------------------------------------------------------
__global__ __launch_bounds__(256) void cast_qcat_kernel(
    const float* __restrict__ query, const float* __restrict__ query_pos,
    ushort* __restrict__ qcat)
{
    const int t = blockIdx.x * 256 + threadIdx.x;    // 4 elems each
    if (t >= NQ * 128) return;
    const int q = t >> 7, c4 = (t & 127) * 4;
    float4 v;
    if (c4 < 256) {
        v = *(const float4*)&query[(size_t)q * 256 + c4];
    } else {
        float4 a = *(const float4*)&query[(size_t)q * 256 + c4 - 256];
        float4 b = *(const float4*)&query_pos[(size_t)q * 256 + c4 - 256];
        v = make_float4(a.x + b.x, a.y + b.y, a.z + b.z, a.w + b.w);
    }
    ushort4 o;
    o.x = f2bf(v.x); o.y = f2bf(v.y); o.z = f2bf(v.z); o.w = f2bf(v.w);
    *(ushort4*)&qcat[(size_t)q * 512 + c4] = o;
}

// ---------------------------------------------------------------------------
// Transpose+cast weights to bf16 N x K layouts; build concat bias
// ---------------------------------------------------------------------------
__global__ __launch_bounds__(256) void prep_weights_kernel(
    const float* __restrict__ Wv, const float* __restrict__ Woff,
    const float* __restrict__ Wattn, const float* __restrict__ Wout,
    const float* __restrict__ boff, const float* __restrict__ battn,
    ushort* __restrict__ WvT, ushort* __restrict__ WoaT,
    ushort* __restrict__ WoutT, float* __restrict__ boa)
{
    int t = blockIdx.x * 256 + threadIdx.x;
    if (t < 65536) { int n = t >> 8, k = t & 255; WvT[t] = f2bf(Wv[k * 256 + n]); return; }
    t -= 65536;
    if (t < 98304) {
        int n = t >> 9, k = t & 511;
        WoaT[t] = f2bf(n < 128 ? Woff[k * 128 + n] : Wattn[k * 64 + (n - 128)]);
        return;
    }
    t -= 98304;
    if (t < 65536) { int n = t >> 8, k = t & 255; WoutT[t] = f2bf(Wout[k * 256 + n]); return; }
    t -= 65536;
    if (t < 192) boa[t] = t < 128 ? boff[t] : battn[t - 128];
}

// ---------------------------------------------------------------------------
// Sampling param precompute: 1 thread per (q,h,j). Packs per point:
// 4 clamped u16 corner indices + 4 bf16 corner weights (incl. softmax, OOB
// validity, and the 0.5 queue-mean factor) into one uint4.
// ---------------------------------------------------------------------------
__global__ __launch_bounds__(256) void msda_prep_kernel(
    const ushort* __restrict__ offattn,  // NQ x 192 bf16: [0,128)=off, [128,192)=attn
    const float* __restrict__ refpts,    // (2, NQ, 1, 2)
    uint4* __restrict__ params)          // (q*8+h)*8 + j*4+p
{
    const int t = blockIdx.x * 256 + threadIdx.x;
    if (t >= NQ * 16) return;
    const int j = t & 1, h = (t >> 1) & 7, q = t >> 4;

    const float rxs = refpts[((size_t)j * NQ + q) * 2 + 0] * 150.f - 0.5f;
    const float rys = refpts[((size_t)j * NQ + q) * 2 + 1] * 150.f - 0.5f;

    const ushort* orow = offattn + (size_t)q * 192 + h * 16 + j * 8;
    const ushort* arow = offattn + (size_t)q * 192 + 128 + h * 8 + j * 4;

    uint2 av = *(const uint2*)arow;
    float al[4] = { bf2f(av.x), bf2f(av.x >> 16), bf2f(av.y), bf2f(av.y >> 16) };
    float m = fmaxf(fmaxf(al[0], al[1]), fmaxf(al[2], al[3]));
    float e[4], s = 0.f;
#pragma unroll
    for (int p = 0; p < 4; ++p) { e[p] = expf(al[p] - m); s += e[p]; }
    const float inv = 0.5f / s;   // queue-mean folded in

    uint4 ov = *(const uint4*)orow;
    uint ow[4] = { ov.x, ov.y, ov.z, ov.w };
#pragma unroll
    for (int p = 0; p < 4; ++p) {
        const float x = rxs + bf2f(ow[p]);
        const float y = rys + bf2f(ow[p] >> 16);
        const float x0f = floorf(x), y0f = floorf(y);
        const float wx = x - x0f, wy = y - y0f;
        const int x0 = (int)x0f, y0 = (int)y0f;
        const float aw = e[p] * inv;
        const float vx0 = (x0 >= 0 && x0 < GW) ? 1.f : 0.f;
        const float vx1 = (x0 >= -1 && x0 < GW - 1) ? 1.f : 0.f;
        const float vy0 = (y0 >= 0 && y0 < GH) ? 1.f : 0.f;
        const float vy1 = (y0 >= -1 && y0 < GH - 1) ? 1.f : 0.f;
        const int ix0 = min(max(x0, 0), GW - 1), ix1 = min(max(x0 + 1, 0), GW - 1);
        const int iy0 = min(max(y0, 0), GH - 1), iy1 = min(max(y0 + 1, 0), GH - 1);
        const float w00 = (1.f - wx) * (1.f - wy) * aw * vx0 * vy0;
        const float w01 = wx * (1.f - wy) * aw * vx1 * vy0;
        const float w10 = (1.f - wx) * wy * aw * vx0 * vy1;
        const float w11 = wx * wy * aw * vx1 * vy1;
        uint4 P;
        P.x = (uint)(iy0 * GW + ix0) | ((uint)(iy0 * GW + ix1) << 16);
        P.y = (uint)(iy1 * GW + ix0) | ((uint)(iy1 * GW + ix1) << 16);
        P.z = (uint)f2bf(w00) | ((uint)f2bf(w01) << 16);
        P.w = (uint)f2bf(w10) | ((uint)f2bf(w11) << 16);
        params[(size_t)t * 4 + p] = P;
    }
}

// ---------------------------------------------------------------------------
// Pure gather: block = 1 query, thread = channel c (h = c>>5).
// ---------------------------------------------------------------------------
__global__ __launch_bounds__(256) void msda_gather_kernel(
    const ushort* __restrict__ value_bf,   // NQ x 256
    const uint4* __restrict__ params,
    ushort* __restrict__ msda_bf)          // NQ x 256
{
    const int q = blockIdx.x;
    const int c = threadIdx.x;
    const int h = c >> 5;
    const uint4* pp = params + ((size_t)q * 8 + h) * 8;
    float acc = 0.f;
#pragma unroll
    for (int pt = 0; pt < 8; ++pt) {
        const uint4 P = pp[pt];
        acc += bf2f(P.z)       * bf2f(value_bf[(size_t)(P.x & 0xffffu) * 256 + c]);
        acc += bf2f(P.z >> 16) * bf2f(value_bf[(size_t)(P.x >> 16)     * 256 + c]);
        acc += bf2f(P.w)       * bf2f(value_bf[(size_t)(P.y & 0xffffu) * 256 + c]);
        acc += bf2f(P.w >> 16) * bf2f(value_bf[(size_t)(P.y >> 16)     * 256 + c]);
    }
    msda_bf[(size_t)q * 256 + c] = f2bf(acc);
}

// ---------------------------------------------------------------------------
extern "C" void kernel_launch(void* const* d_in, const int* in_sizes, int n_in,
                              void* d_out, int out_size, void* d_ws, size_t ws_size,
                              hipStream_t stream)
{
    const float* query     = (const float*)d_in[0];
    const float* query_pos = (const float*)d_in[1];
    const float* refpts    = (const float*)d_in[2];
    const float* W_off     = (const float*)d_in[3];
    const float* b_off     = (const float*)d_in[4];
    const float* W_attn    = (const float*)d_in[5];
    const float* b_attn    = (const float*)d_in[6];
    const float* W_v       = (const float*)d_in[7];
    const float* b_v       = (const float*)d_in[8];
    const float* W_out     = (const float*)d_in[9];
    const float* b_out     = (const float*)d_in[10];
    float* out             = (float*)d_out;

    char* base = (char*)d_ws;
    size_t o = 0;
    ushort* value_bf = (ushort*)(base + o); o += (size_t)NQP * 256 * 2;
    ushort* offattn  = (ushort*)(base + o); o += (size_t)NQP * 192 * 2;
    ushort* qcat     = (ushort*)(base + o); o += (size_t)NQP * 512 * 2;
    ushort* msda_bf  = (ushort*)(base + o); o += (size_t)NQP * 256 * 2;
    ushort* WvT      = (ushort*)(base + o); o += 256 * 256 * 2;
    ushort* WoaT     = (ushort*)(base + o); o += 192 * 512 * 2;
    ushort* WoutT    = (ushort*)(base + o); o += 256 * 256 * 2;
    float*  boa      = (float*)(base + o);  o += 192 * 4;
    // params alias qcat (dead after GEMM2+3): 1.44M * 16B = 23.04MB <= 23.07MB
    uint4* params = (uint4*)qcat;

    const int mblocks = NQP / 128;   // 176

    cast_qcat_kernel<<<(NQ * 128 + 255) / 256, 256, 0, stream>>>(query, query_pos, qcat);
    prep_weights_kernel<<<(229568 + 255) / 256, 256, 0, stream>>>(
        W_v, W_off, W_attn, W_out, b_off, b_attn, WvT, WoaT, WoutT, boa);

    // value = query @ W_v + b_v   (A = first 256 cols of qcat, lda=512)
    gemm_bf16_kernel<0><<<dim3(mblocks, 4), 256, 0, stream>>>(
        qcat, 512, WvT, b_v, nullptr, value_bf, 256, NQ, 256, 256);

    // [off|attn] = qcat @ [W_off|W_attn]
    gemm_bf16_kernel<0><<<dim3(mblocks, 3), 256, 0, stream>>>(
        qcat, 512, WoaT, boa, nullptr, offattn, 192, NQ, 192, 512);

    msda_prep_kernel<<<(NQ * 16 + 255) / 256, 256, 0, stream>>>(offattn, refpts, params);

    msda_gather_kernel<<<NQ, 256, 0, stream>>>(value_bf, params, msda_bf);

    // out = msda @ W_out + b_out + query
    gemm_bf16_kernel<1><<<dim3(mblocks, 4), 256, 0, stream>>>(
        msda_bf, 256, WoutT, b_out, query, out, 256, NQ, 256, 256);
}

// Round 3
// 105.835 us; speedup vs baseline: 4.3165x; 1.1069x over previous
//
#include <hip/hip_runtime.h>
#include <hip/hip_bf16.h>
#include <math.h>

constexpr int NQ   = 22500;      // 150*150
constexpr int NQP  = 22528;      // padded to 176*128
constexpr int GH   = 150, GW = 150;
constexpr int EMBED = 256;

using f32x4 = __attribute__((ext_vector_type(4))) float;
using s16x8 = __attribute__((ext_vector_type(8))) short;

__device__ inline ushort f2bf(float f) {
    __hip_bfloat16 h = __float2bfloat16(f);
    return *reinterpret_cast<ushort*>(&h);
}
__device__ inline float bf2f(uint u) {
    uint x = (u & 0xffffu) << 16;
    return __builtin_bit_cast(float, x);
}
// low bf16 of a packed uint -> f32
__device__ inline float bflo(uint u) {
    return __builtin_bit_cast(float, u << 16);
}
// high bf16 of a packed uint -> f32
__device__ inline float bfhi(uint u) {
    return __builtin_bit_cast(float, u & 0xffff0000u);
}

__device__ inline void gload_lds16(const void* g, void* l) {
    __builtin_amdgcn_global_load_lds(
        (const __attribute__((address_space(1))) void*)g,
        (__attribute__((address_space(3))) void*)l, 16, 0, 0);
}

// ---------------------------------------------------------------------------
// bf16 MFMA GEMM: C[M,N] = A[M,K](bf16,row-major,lda) @ Bt[N,K](bf16)^T
//                 + bias (+ identity if OUT_MODE==1)
// OUT_MODE 0: store bf16 (ldc), 1: store f32 + identity
// Tile: BM=128, BN=64, BK=32; 256 threads = 4 waves in 2x2.
// ---------------------------------------------------------------------------
template <int OUT_MODE>
__global__ __launch_bounds__(256) void gemm_bf16_kernel(
    const ushort* __restrict__ A, int lda,
    const ushort* __restrict__ Bt,
    const float* __restrict__ bias,
    const float* __restrict__ ident,
    void* __restrict__ Cout, int ldc,
    int M, int N, int K)
{
    constexpr int BM = 128, BN = 64, BK = 32;
    __shared__ ushort As[BM * BK];   // [row][k], 64B per row
    __shared__ ushort Bs[BN * BK];   // [col][k]

    const int tid  = threadIdx.x;
    const int lane = tid & 63;
    const int w    = tid >> 6;
    const int wm   = w >> 1, wn = w & 1;
    const int l15  = lane & 15, l4 = lane >> 4;
    const int brow = blockIdx.x * BM;
    const int bcol = blockIdx.y * BN;

    f32x4 acc[4][2] = {};

    for (int k0 = 0; k0 < K; k0 += BK) {
        // Stage A: 128x32 bf16 = 8KB = 2 chunks of (256 lanes x 16B)
#pragma unroll
        for (int c = 0; c < 2; ++c) {
            const int idx = c * 256 + tid;                 // linear 16B chunk id
            const ushort* src = A + (size_t)(brow + (idx >> 2)) * lda + k0 + (idx & 3) * 8;
            gload_lds16(src, (char*)As + (c * 256 + w * 64) * 16);
        }
        // Stage B: 64x32 bf16 = 4KB = 1 chunk
        {
            const int idx = tid;
            const ushort* src = Bt + (size_t)(bcol + (idx >> 2)) * K + k0 + (idx & 3) * 8;
            gload_lds16(src, (char*)Bs + (w * 64) * 16);
        }
        __syncthreads();

        s16x8 a[4], b[2];
#pragma unroll
        for (int mi = 0; mi < 4; ++mi)
            a[mi] = *(const s16x8*)&As[(wm * 64 + mi * 16 + l15) * BK + l4 * 8];
#pragma unroll
        for (int ni = 0; ni < 2; ++ni)
            b[ni] = *(const s16x8*)&Bs[(wn * 32 + ni * 16 + l15) * BK + l4 * 8];
#pragma unroll
        for (int mi = 0; mi < 4; ++mi)
#pragma unroll
            for (int ni = 0; ni < 2; ++ni)
                acc[mi][ni] = __builtin_amdgcn_mfma_f32_16x16x32_bf16(
                    a[mi], b[ni], acc[mi][ni], 0, 0, 0);
        __syncthreads();
    }

    // Epilogue: C/D layout col=lane&15, row=(lane>>4)*4+r
#pragma unroll
    for (int mi = 0; mi < 4; ++mi) {
#pragma unroll
        for (int r = 0; r < 4; ++r) {
            const int gr = brow + wm * 64 + mi * 16 + l4 * 4 + r;
            if (gr >= M) continue;
#pragma unroll
            for (int ni = 0; ni < 2; ++ni) {
                const int gc = bcol + wn * 32 + ni * 16 + l15;
                float v = acc[mi][ni][r] + bias[gc];
                if (OUT_MODE == 1) {
                    v += ident[(size_t)gr * ldc + gc];
                    ((float*)Cout)[(size_t)gr * ldc + gc] = v;
                } else {
                    ((ushort*)Cout)[(size_t)gr * ldc + gc] = f2bf(v);
                }
            }
        }
    }
}

// ---------------------------------------------------------------------------
// Build q_cat bf16: row q = [query | query+query_pos], NQ x 512
// ---------------------------------------------------------------------------
__global__ __launch_bounds__(256) void cast_qcat_kernel(
    const float* __restrict__ query, const float* __restrict__ query_pos,
    ushort* __restrict__ qcat)
{
    const int t = blockIdx.x * 256 + threadIdx.x;    // 4 elems each
    if (t >= NQ * 128) return;
    const int q = t >> 7, c4 = (t & 127) * 4;
    float4 v;
    if (c4 < 256) {
        v = *(const float4*)&query[(size_t)q * 256 + c4];
    } else {
        float4 a = *(const float4*)&query[(size_t)q * 256 + c4 - 256];
        float4 b = *(const float4*)&query_pos[(size_t)q * 256 + c4 - 256];
        v = make_float4(a.x + b.x, a.y + b.y, a.z + b.z, a.w + b.w);
    }
    ushort4 o;
    o.x = f2bf(v.x); o.y = f2bf(v.y); o.z = f2bf(v.z); o.w = f2bf(v.w);
    *(ushort4*)&qcat[(size_t)q * 512 + c4] = o;
}

// ---------------------------------------------------------------------------
// Transpose+cast weights to bf16 N x K layouts; build concat bias
// ---------------------------------------------------------------------------
__global__ __launch_bounds__(256) void prep_weights_kernel(
    const float* __restrict__ Wv, const float* __restrict__ Woff,
    const float* __restrict__ Wattn, const float* __restrict__ Wout,
    const float* __restrict__ boff, const float* __restrict__ battn,
    ushort* __restrict__ WvT, ushort* __restrict__ WoaT,
    ushort* __restrict__ WoutT, float* __restrict__ boa)
{
    int t = blockIdx.x * 256 + threadIdx.x;
    if (t < 65536) { int n = t >> 8, k = t & 255; WvT[t] = f2bf(Wv[k * 256 + n]); return; }
    t -= 65536;
    if (t < 98304) {
        int n = t >> 9, k = t & 511;
        WoaT[t] = f2bf(n < 128 ? Woff[k * 128 + n] : Wattn[k * 64 + (n - 128)]);
        return;
    }
    t -= 98304;
    if (t < 65536) { int n = t >> 8, k = t & 255; WoutT[t] = f2bf(Wout[k * 256 + n]); return; }
    t -= 65536;
    if (t < 192) boa[t] = t < 128 ? boff[t] : battn[t - 128];
}

// ---------------------------------------------------------------------------
// Sampling param precompute: 1 thread per (q,h,j). Packs per point:
// 4 clamped u16 corner indices + 4 bf16 corner weights (incl. softmax, OOB
// validity, and the 0.5 queue-mean factor) into one uint4.
// ---------------------------------------------------------------------------
__global__ __launch_bounds__(256) void msda_prep_kernel(
    const ushort* __restrict__ offattn,  // NQ x 192 bf16: [0,128)=off, [128,192)=attn
    const float* __restrict__ refpts,    // (2, NQ, 1, 2)
    uint4* __restrict__ params)          // (q*8+h)*8 + j*4+p
{
    const int t = blockIdx.x * 256 + threadIdx.x;
    if (t >= NQ * 16) return;
    const int j = t & 1, h = (t >> 1) & 7, q = t >> 4;

    const float rxs = refpts[((size_t)j * NQ + q) * 2 + 0] * 150.f - 0.5f;
    const float rys = refpts[((size_t)j * NQ + q) * 2 + 1] * 150.f - 0.5f;

    const ushort* orow = offattn + (size_t)q * 192 + h * 16 + j * 8;
    const ushort* arow = offattn + (size_t)q * 192 + 128 + h * 8 + j * 4;

    uint2 av = *(const uint2*)arow;
    float al[4] = { bf2f(av.x), bf2f(av.x >> 16), bf2f(av.y), bf2f(av.y >> 16) };
    float m = fmaxf(fmaxf(al[0], al[1]), fmaxf(al[2], al[3]));
    float e[4], s = 0.f;
#pragma unroll
    for (int p = 0; p < 4; ++p) { e[p] = expf(al[p] - m); s += e[p]; }
    const float inv = 0.5f / s;   // queue-mean folded in

    uint4 ov = *(const uint4*)orow;
    uint ow[4] = { ov.x, ov.y, ov.z, ov.w };
#pragma unroll
    for (int p = 0; p < 4; ++p) {
        const float x = rxs + bf2f(ow[p]);
        const float y = rys + bf2f(ow[p] >> 16);
        const float x0f = floorf(x), y0f = floorf(y);
        const float wx = x - x0f, wy = y - y0f;
        const int x0 = (int)x0f, y0 = (int)y0f;
        const float aw = e[p] * inv;
        const float vx0 = (x0 >= 0 && x0 < GW) ? 1.f : 0.f;
        const float vx1 = (x0 >= -1 && x0 < GW - 1) ? 1.f : 0.f;
        const float vy0 = (y0 >= 0 && y0 < GH) ? 1.f : 0.f;
        const float vy1 = (y0 >= -1 && y0 < GH - 1) ? 1.f : 0.f;
        const int ix0 = min(max(x0, 0), GW - 1), ix1 = min(max(x0 + 1, 0), GW - 1);
        const int iy0 = min(max(y0, 0), GH - 1), iy1 = min(max(y0 + 1, 0), GH - 1);
        const float w00 = (1.f - wx) * (1.f - wy) * aw * vx0 * vy0;
        const float w01 = wx * (1.f - wy) * aw * vx1 * vy0;
        const float w10 = (1.f - wx) * wy * aw * vx0 * vy1;
        const float w11 = wx * wy * aw * vx1 * vy1;
        uint4 P;
        P.x = (uint)(iy0 * GW + ix0) | ((uint)(iy0 * GW + ix1) << 16);
        P.y = (uint)(iy1 * GW + ix0) | ((uint)(iy1 * GW + ix1) << 16);
        P.z = (uint)f2bf(w00) | ((uint)f2bf(w01) << 16);
        P.w = (uint)f2bf(w10) | ((uint)f2bf(w11) << 16);
        params[(size_t)t * 4 + p] = P;
    }
}

// ---------------------------------------------------------------------------
// Pure gather, v2: 1 wave per query; lane = h*8+cl; each lane owns 4 channels
// (c0 = h*32 + cl*4) loaded as uint2 (4 bf16). XCD-chunked block swizzle.
// ---------------------------------------------------------------------------
__global__ __launch_bounds__(256) void msda_gather_kernel(
    const ushort* __restrict__ value_bf,   // NQ x 256
    const uint4* __restrict__ params,      // (NQ*8) x 8
    ushort* __restrict__ msda_bf)          // NQ x 256
{
    // bijective XCD swizzle over NB = 5625 blocks (m204 formula)
    constexpr int NB = NQ / 4;         // 5625
    constexpr int NX = 8;
    constexpr int qd = NB / NX;        // 703
    constexpr int rr = NB % NX;        // 1
    const int bid = blockIdx.x;
    const int xcd = bid % NX, loc = bid / NX;
    const int swz = (xcd < rr ? xcd * (qd + 1) : rr * (qd + 1) + (xcd - rr) * qd) + loc;

    const int wv   = threadIdx.x >> 6;
    const int lane = threadIdx.x & 63;
    const int h    = lane >> 3;
    const int cl   = lane & 7;
    const int q    = swz * 4 + wv;
    const int c0   = h * 32 + cl * 4;          // channel base
    const uint cb  = (uint)c0 * 2;             // byte offset within a value row

    const uint4* pp = params + ((size_t)q * 8 + h) * 8;
    const char* vbase = (const char*)value_bf;

    float a0 = 0.f, a1 = 0.f, a2 = 0.f, a3 = 0.f;

#pragma unroll
    for (int pt = 0; pt < 8; ++pt) {
        const uint4 P = pp[pt];
#pragma unroll
        for (int cr = 0; cr < 4; ++cr) {
            const uint idxw = (cr < 2) ? P.x : P.y;
            const uint wpk  = (cr < 2) ? P.z : P.w;
            const uint pix  = (cr & 1) ? (idxw >> 16) : (idxw & 0xffffu);
            const float w   = (cr & 1) ? bfhi(wpk) : bflo(wpk);
            const uint2 v = *(const uint2*)(vbase + ((size_t)(pix << 9) + cb));
            a0 = fmaf(w, bflo(v.x), a0);
            a1 = fmaf(w, bfhi(v.x), a1);
            a2 = fmaf(w, bflo(v.y), a2);
            a3 = fmaf(w, bfhi(v.y), a3);
        }
    }

    ushort4 o;
    o.x = f2bf(a0); o.y = f2bf(a1); o.z = f2bf(a2); o.w = f2bf(a3);
    *(ushort4*)&msda_bf[(size_t)q * 256 + c0] = o;
}

// ---------------------------------------------------------------------------
extern "C" void kernel_launch(void* const* d_in, const int* in_sizes, int n_in,
                              void* d_out, int out_size, void* d_ws, size_t ws_size,
                              hipStream_t stream)
{
    const float* query     = (const float*)d_in[0];
    const float* query_pos = (const float*)d_in[1];
    const float* refpts    = (const float*)d_in[2];
    const float* W_off     = (const float*)d_in[3];
    const float* b_off     = (const float*)d_in[4];
    const float* W_attn    = (const float*)d_in[5];
    const float* b_attn    = (const float*)d_in[6];
    const float* W_v       = (const float*)d_in[7];
    const float* b_v       = (const float*)d_in[8];
    const float* W_out     = (const float*)d_in[9];
    const float* b_out     = (const float*)d_in[10];
    float* out             = (float*)d_out;

    char* base = (char*)d_ws;
    size_t o = 0;
    ushort* value_bf = (ushort*)(base + o); o += (size_t)NQP * 256 * 2;
    ushort* offattn  = (ushort*)(base + o); o += (size_t)NQP * 192 * 2;
    ushort* qcat     = (ushort*)(base + o); o += (size_t)NQP * 512 * 2;
    ushort* msda_bf  = (ushort*)(base + o); o += (size_t)NQP * 256 * 2;
    ushort* WvT      = (ushort*)(base + o); o += 256 * 256 * 2;
    ushort* WoaT     = (ushort*)(base + o); o += 192 * 512 * 2;
    ushort* WoutT    = (ushort*)(base + o); o += 256 * 256 * 2;
    float*  boa      = (float*)(base + o);  o += 192 * 4;
    // params alias qcat (dead after GEMM2+3): 1.44M * 16B = 23.04MB <= 23.07MB
    uint4* params = (uint4*)qcat;

    const int mblocks = NQP / 128;   // 176

    cast_qcat_kernel<<<(NQ * 128 + 255) / 256, 256, 0, stream>>>(query, query_pos, qcat);
    prep_weights_kernel<<<(229568 + 255) / 256, 256, 0, stream>>>(
        W_v, W_off, W_attn, W_out, b_off, b_attn, WvT, WoaT, WoutT, boa);

    // value = query @ W_v + b_v   (A = first 256 cols of qcat, lda=512)
    gemm_bf16_kernel<0><<<dim3(mblocks, 4), 256, 0, stream>>>(
        qcat, 512, WvT, b_v, nullptr, value_bf, 256, NQ, 256, 256);

    // [off|attn] = qcat @ [W_off|W_attn]
    gemm_bf16_kernel<0><<<dim3(mblocks, 3), 256, 0, stream>>>(
        qcat, 512, WoaT, boa, nullptr, offattn, 192, NQ, 192, 512);

    msda_prep_kernel<<<(NQ * 16 + 255) / 256, 256, 0, stream>>>(offattn, refpts, params);

    msda_gather_kernel<<<NQ / 4, 256, 0, stream>>>(value_bf, params, msda_bf);

    // out = msda @ W_out + b_out + query
    gemm_bf16_kernel<1><<<dim3(mblocks, 4), 256, 0, stream>>>(
        msda_bf, 256, WoutT, b_out, query, out, 256, NQ, 256, 256);
}

// Round 4
// 102.620 us; speedup vs baseline: 4.4517x; 1.0313x over previous
//
#include <hip/hip_runtime.h>
#include <hip/hip_bf16.h>
#include <math.h>

constexpr int NQ   = 22500;      // 150*150
constexpr int NQP  = 22528;      // padded to 352*64
constexpr int GH   = 150, GW = 150;

using f32x4 = __attribute__((ext_vector_type(4))) float;
using s16x8 = __attribute__((ext_vector_type(8))) short;

__device__ inline ushort f2bf(float f) {
    __hip_bfloat16 h = __float2bfloat16(f);
    return *reinterpret_cast<ushort*>(&h);
}
__device__ inline float bflo(uint u) { return __builtin_bit_cast(float, u << 16); }
__device__ inline float bfhi(uint u) { return __builtin_bit_cast(float, u & 0xffff0000u); }
__device__ inline float bf2f(uint u) { return __builtin_bit_cast(float, (u & 0xffffu) << 16); }

__device__ inline void gload_lds16(const void* g, void* l) {
    __builtin_amdgcn_global_load_lds(
        (const __attribute__((address_space(1))) void*)g,
        (__attribute__((address_space(3))) void*)l, 16, 0, 0);
}

// ---------------------------------------------------------------------------
// Fused front: qcat(bf16, LDS) = [query | query+query_pos]; then
// [value | off | attn] = qcat @ Bcat  (Bcat = 448 x 512, col-major-K, bf16)
// value tiles (cols 0..255) use K=256 only; off/attn tiles use K=512.
// Block: 64 rows, 4 waves (2x2 over 64x64 N-tile). LDS: A 64KB + B 2x8KB.
// A LDS is XOR-swizzled (phys 16B-slot ^= row&7) on both write & read.
// B chunks staged via global_load_lds with source-address swizzle (m173).
// ---------------------------------------------------------------------------
__global__ __launch_bounds__(256, 2) void fused_front_kernel(
    const float* __restrict__ query, const float* __restrict__ qpos,
    const ushort* __restrict__ Bcat, const float* __restrict__ bcat,
    ushort* __restrict__ value_bf,   // NQ x 256
    ushort* __restrict__ offattn)    // NQ x 192
{
    __shared__ ushort Alds[64 * 512];     // 64 KB
    __shared__ ushort Blds[2][64 * 64];   // 2 x 8 KB

    const int tid  = threadIdx.x;
    const int lane = tid & 63;
    const int w    = tid >> 6;
    const int wm   = w >> 1, wn = w & 1;
    const int l15  = lane & 15, l4 = lane >> 4;
    const int brow = blockIdx.x * 64;

    // ---- issue first B chunk (tile 0, kc 0) ----
#pragma unroll
    for (int c = 0; c < 2; ++c) {
        const int idx = c * 256 + tid;
        const ushort* src = Bcat + (size_t)(idx >> 3) * 512 + (((idx & 7) ^ ((idx >> 3) & 7)) << 3);
        gload_lds16(src, (char*)Blds[0] + (c * 256 + w * 64) * 16);
    }

    // ---- stage A: build bf16 qcat tile in swizzled LDS ----
    {
        const int row = tid >> 2;
        const int cb  = (tid & 3) * 64;
        const int row_g = brow + row;
        const bool ok = row_g < NQ;
        const float4* qrow = (const float4*)(query + (size_t)row_g * 256 + cb);
        const float4* prow = (const float4*)(qpos  + (size_t)row_g * 256 + cb);
        const uint sw = (uint)(row & 7) << 4;
#pragma unroll
        for (int ci = 0; ci < 8; ++ci) {
            float4 qa = {}, qb = {}, pa = {}, pb = {};
            if (ok) { qa = qrow[ci*2]; qb = qrow[ci*2+1]; pa = prow[ci*2]; pb = prow[ci*2+1]; }
            s16x8 LW, RW;
            LW[0]=f2bf(qa.x); LW[1]=f2bf(qa.y); LW[2]=f2bf(qa.z); LW[3]=f2bf(qa.w);
            LW[4]=f2bf(qb.x); LW[5]=f2bf(qb.y); LW[6]=f2bf(qb.z); LW[7]=f2bf(qb.w);
            RW[0]=f2bf(qa.x+pa.x); RW[1]=f2bf(qa.y+pa.y); RW[2]=f2bf(qa.z+pa.z); RW[3]=f2bf(qa.w+pa.w);
            RW[4]=f2bf(qb.x+pb.x); RW[5]=f2bf(qb.y+pb.y); RW[6]=f2bf(qb.z+pb.z); RW[7]=f2bf(qb.w+pb.w);
            const int kL = cb + ci * 8, kR = 256 + kL;
            *(s16x8*)((char*)Alds + row * 1024 + (((uint)(kL * 2)) ^ sw)) = LW;
            *(s16x8*)((char*)Alds + row * 1024 + (((uint)(kR * 2)) ^ sw)) = RW;
        }
    }
    __syncthreads();

    // ---- main loop: 40 chunks = 4 value tiles x4 + 3 offattn tiles x8 ----
    f32x4 acc[2][2];
    int buf = 0;
    const int rowA0 = wm * 32 + l15;          // mi adds 16
    const int colB0 = wn * 32 + l15;          // ni adds 16

    for (int ci = 0; ci < 40; ++ci) {
        int nt, kc, lastkc;
        if (ci < 16) { nt = ci >> 2; kc = ci & 3; lastkc = 3; }
        else         { int cj = ci - 16; nt = 4 + (cj >> 3); kc = cj & 7; lastkc = 7; }

        if (kc == 0) {
#pragma unroll
            for (int mi = 0; mi < 2; ++mi)
#pragma unroll
                for (int ni = 0; ni < 2; ++ni) acc[mi][ni] = (f32x4){0.f,0.f,0.f,0.f};
        }

        // issue next chunk into the other buffer
        if (ci + 1 < 40) {
            int nt2, kc2;
            if (ci + 1 < 16) { nt2 = (ci+1) >> 2; kc2 = (ci+1) & 3; }
            else             { int cj = ci + 1 - 16; nt2 = 4 + (cj >> 3); kc2 = cj & 7; }
#pragma unroll
            for (int c = 0; c < 2; ++c) {
                const int idx = c * 256 + tid;
                const ushort* src = Bcat + (size_t)(nt2 * 64 + (idx >> 3)) * 512 + kc2 * 64
                                  + (((idx & 7) ^ ((idx >> 3) & 7)) << 3);
                gload_lds16(src, (char*)Blds[buf ^ 1] + (c * 256 + w * 64) * 16);
            }
        }

        // compute current chunk (K=64 -> 2 MFMA K-steps)
#pragma unroll
        for (int ks = 0; ks < 2; ++ks) {
            const int kel = kc * 64 + ks * 32 + l4 * 8;
            s16x8 a[2], b[2];
#pragma unroll
            for (int mi = 0; mi < 2; ++mi) {
                const int row = rowA0 + mi * 16;
                a[mi] = *(const s16x8*)((char*)Alds + row * 1024
                          + (((uint)(kel * 2)) ^ ((uint)(row & 7) << 4)));
            }
#pragma unroll
            for (int ni = 0; ni < 2; ++ni) {
                const int col = colB0 + ni * 16;
                b[ni] = *(const s16x8*)((char*)Blds[buf] + col * 128
                          + (((uint)((ks * 32 + l4 * 8) * 2)) ^ ((uint)(col & 7) << 4)));
            }
#pragma unroll
            for (int mi = 0; mi < 2; ++mi)
#pragma unroll
                for (int ni = 0; ni < 2; ++ni)
                    acc[mi][ni] = __builtin_amdgcn_mfma_f32_16x16x32_bf16(
                        a[mi], b[ni], acc[mi][ni], 0, 0, 0);
        }

        if (kc == lastkc) {
            // epilogue for tile nt
#pragma unroll
            for (int mi = 0; mi < 2; ++mi) {
#pragma unroll
                for (int r = 0; r < 4; ++r) {
                    const int gr = brow + wm * 32 + mi * 16 + l4 * 4 + r;
                    if (gr >= NQ) continue;
#pragma unroll
                    for (int ni = 0; ni < 2; ++ni) {
                        const int gc = nt * 64 + wn * 32 + ni * 16 + l15;
                        const float v = acc[mi][ni][r] + bcat[gc];
                        if (gc < 256) value_bf[(size_t)gr * 256 + gc] = f2bf(v);
                        else          offattn[(size_t)gr * 192 + gc - 256] = f2bf(v);
                    }
                }
            }
        }
        __syncthreads();
        buf ^= 1;
    }
}

// ---------------------------------------------------------------------------
// Weight prep: Bcat[448][512] = [W_v(K<=256,zero-pad) | W_off | W_attn]^T,
// WoutT[256][256], bcat[448] = [b_v | b_off | b_attn]
// ---------------------------------------------------------------------------
__global__ __launch_bounds__(256) void prep_weights_kernel(
    const float* __restrict__ Wv, const float* __restrict__ Woff,
    const float* __restrict__ Wattn, const float* __restrict__ Wout,
    const float* __restrict__ bv, const float* __restrict__ boff,
    const float* __restrict__ battn,
    ushort* __restrict__ Bcat, ushort* __restrict__ WoutT, float* __restrict__ bcat)
{
    int t = blockIdx.x * 256 + threadIdx.x;
    if (t < 448 * 512) {
        const int col = t >> 9, k = t & 511;
        float v;
        if (col < 256)      v = (k < 256) ? Wv[k * 256 + col] : 0.f;
        else if (col < 384) v = Woff[k * 128 + (col - 256)];
        else                v = Wattn[k * 64 + (col - 384)];
        Bcat[t] = f2bf(v);
        return;
    }
    t -= 448 * 512;
    if (t < 65536) { const int n = t >> 8, k = t & 255; WoutT[t] = f2bf(Wout[k * 256 + n]); return; }
    t -= 65536;
    if (t < 448) bcat[t] = t < 256 ? bv[t] : (t < 384 ? boff[t - 256] : battn[t - 384]);
}

// ---------------------------------------------------------------------------
// Fused prep + gather. Block = 4 waves = 4 queries (XCD-swizzled).
// Prep: lane = h*8 + j*4 + p computes one point's packed record
// (4 clamped pixel idx u16 + 4 bf16 weights incl softmax & 0.5 queue-mean),
// softmax over p via 4-lane shfl_xor. Shared via LDS, then pure gather:
// lane = h*8+cl owns 4 channels (uint2 loads).
// ---------------------------------------------------------------------------
__global__ __launch_bounds__(256) void msda_fused_kernel(
    const ushort* __restrict__ value_bf,   // NQ x 256
    const ushort* __restrict__ offattn,    // NQ x 192
    const float* __restrict__ refpts,      // (2, NQ, 1, 2)
    ushort* __restrict__ msda_bf)          // NQ x 256
{
    __shared__ uint4 Plds[4 * 64];

    constexpr int NB = NQ / 4;         // 5625
    constexpr int NX = 8;
    constexpr int qd = NB / NX, rr = NB % NX;
    const int bid = blockIdx.x;
    const int xcd = bid % NX, loc = bid / NX;
    const int swz = (xcd < rr ? xcd * (qd + 1) : rr * (qd + 1) + (xcd - rr) * qd) + loc;

    const int wv   = threadIdx.x >> 6;
    const int lane = threadIdx.x & 63;
    const int q    = swz * 4 + wv;

    // ---- prep: one point per lane ----
    {
        const int jj = (lane >> 2) & 1;
        const float lg = bf2f(offattn[(size_t)q * 192 + 128 + lane]);
        float mx = fmaxf(lg, __shfl_xor(lg, 1));
        mx = fmaxf(mx, __shfl_xor(mx, 2));
        const float e = expf(lg - mx);
        float s = e + __shfl_xor(e, 1);
        s = s + __shfl_xor(s, 2);
        const float aw = e * (0.5f / s);

        const uint opk = *(const uint*)(offattn + (size_t)q * 192 + lane * 2);
        const float2 rp = *(const float2*)(refpts + ((size_t)jj * NQ + q) * 2);
        const float x = rp.x * 150.f - 0.5f + bflo(opk);
        const float y = rp.y * 150.f - 0.5f + bfhi(opk);
        const float x0f = floorf(x), y0f = floorf(y);
        const float wx = x - x0f, wy = y - y0f;
        const int x0 = (int)x0f, y0 = (int)y0f;
        const float vx0 = (x0 >= 0 && x0 < GW) ? 1.f : 0.f;
        const float vx1 = (x0 >= -1 && x0 < GW - 1) ? 1.f : 0.f;
        const float vy0 = (y0 >= 0 && y0 < GH) ? 1.f : 0.f;
        const float vy1 = (y0 >= -1 && y0 < GH - 1) ? 1.f : 0.f;
        const int ix0 = min(max(x0, 0), GW - 1), ix1 = min(max(x0 + 1, 0), GW - 1);
        const int iy0 = min(max(y0, 0), GH - 1), iy1 = min(max(y0 + 1, 0), GH - 1);
        const float w00 = (1.f - wx) * (1.f - wy) * aw * vx0 * vy0;
        const float w01 = wx * (1.f - wy) * aw * vx1 * vy0;
        const float w10 = (1.f - wx) * wy * aw * vx0 * vy1;
        const float w11 = wx * wy * aw * vx1 * vy1;
        uint4 P;
        P.x = (uint)(iy0 * GW + ix0) | ((uint)(iy0 * GW + ix1) << 16);
        P.y = (uint)(iy1 * GW + ix0) | ((uint)(iy1 * GW + ix1) << 16);
        P.z = (uint)f2bf(w00) | ((uint)f2bf(w01) << 16);
        P.w = (uint)f2bf(w10) | ((uint)f2bf(w11) << 16);
        Plds[wv * 64 + lane] = P;
    }
    __syncthreads();

    // ---- gather ----
    const int h  = lane >> 3;
    const int cl = lane & 7;
    const int c0 = h * 32 + cl * 4;
    const uint cb = (uint)c0 * 2;
    const uint4* pp = &Plds[wv * 64 + h * 8];
    const char* vbase = (const char*)value_bf;

    float a0 = 0.f, a1 = 0.f, a2 = 0.f, a3 = 0.f;
#pragma unroll
    for (int pt = 0; pt < 8; ++pt) {
        const uint4 P = pp[pt];
#pragma unroll
        for (int cr = 0; cr < 4; ++cr) {
            const uint idxw = (cr < 2) ? P.x : P.y;
            const uint wpk  = (cr < 2) ? P.z : P.w;
            const uint pix  = (cr & 1) ? (idxw >> 16) : (idxw & 0xffffu);
            const float wgt = (cr & 1) ? bfhi(wpk) : bflo(wpk);
            const uint2 v = *(const uint2*)(vbase + ((size_t)(pix << 9) + cb));
            a0 = fmaf(wgt, bflo(v.x), a0);
            a1 = fmaf(wgt, bfhi(v.x), a1);
            a2 = fmaf(wgt, bflo(v.y), a2);
            a3 = fmaf(wgt, bfhi(v.y), a3);
        }
    }
    ushort4 o;
    o.x = f2bf(a0); o.y = f2bf(a1); o.z = f2bf(a2); o.w = f2bf(a3);
    *(ushort4*)&msda_bf[(size_t)q * 256 + c0] = o;
}

// ---------------------------------------------------------------------------
// Classic bf16 MFMA GEMM for the output projection (+bias +identity, f32 out)
// ---------------------------------------------------------------------------
__global__ __launch_bounds__(256) void gemm_out_kernel(
    const ushort* __restrict__ A, const ushort* __restrict__ Bt,
    const float* __restrict__ bias, const float* __restrict__ ident,
    float* __restrict__ C, int M)
{
    constexpr int BK = 32;
    __shared__ ushort As[128 * BK];
    __shared__ ushort Bs[64 * BK];

    const int tid  = threadIdx.x;
    const int lane = tid & 63;
    const int w    = tid >> 6;
    const int wm   = w >> 1, wn = w & 1;
    const int l15  = lane & 15, l4 = lane >> 4;
    const int brow = blockIdx.x * 128;
    const int bcol = blockIdx.y * 64;

    f32x4 acc[4][2] = {};

    for (int k0 = 0; k0 < 256; k0 += BK) {
#pragma unroll
        for (int c = 0; c < 2; ++c) {
            const int idx = c * 256 + tid;
            const ushort* src = A + (size_t)(brow + (idx >> 2)) * 256 + k0 + (idx & 3) * 8;
            gload_lds16(src, (char*)As + (c * 256 + w * 64) * 16);
        }
        {
            const int idx = tid;
            const ushort* src = Bt + (size_t)(bcol + (idx >> 2)) * 256 + k0 + (idx & 3) * 8;
            gload_lds16(src, (char*)Bs + (w * 64) * 16);
        }
        __syncthreads();

        s16x8 a[4], b[2];
#pragma unroll
        for (int mi = 0; mi < 4; ++mi)
            a[mi] = *(const s16x8*)&As[(wm * 64 + mi * 16 + l15) * BK + l4 * 8];
#pragma unroll
        for (int ni = 0; ni < 2; ++ni)
            b[ni] = *(const s16x8*)&Bs[(wn * 32 + ni * 16 + l15) * BK + l4 * 8];
#pragma unroll
        for (int mi = 0; mi < 4; ++mi)
#pragma unroll
            for (int ni = 0; ni < 2; ++ni)
                acc[mi][ni] = __builtin_amdgcn_mfma_f32_16x16x32_bf16(
                    a[mi], b[ni], acc[mi][ni], 0, 0, 0);
        __syncthreads();
    }

#pragma unroll
    for (int mi = 0; mi < 4; ++mi) {
#pragma unroll
        for (int r = 0; r < 4; ++r) {
            const int gr = brow + wm * 64 + mi * 16 + l4 * 4 + r;
            if (gr >= M) continue;
#pragma unroll
            for (int ni = 0; ni < 2; ++ni) {
                const int gc = bcol + wn * 32 + ni * 16 + l15;
                C[(size_t)gr * 256 + gc] = acc[mi][ni][r] + bias[gc] + ident[(size_t)gr * 256 + gc];
            }
        }
    }
}

// ---------------------------------------------------------------------------
extern "C" void kernel_launch(void* const* d_in, const int* in_sizes, int n_in,
                              void* d_out, int out_size, void* d_ws, size_t ws_size,
                              hipStream_t stream)
{
    const float* query     = (const float*)d_in[0];
    const float* query_pos = (const float*)d_in[1];
    const float* refpts    = (const float*)d_in[2];
    const float* W_off     = (const float*)d_in[3];
    const float* b_off     = (const float*)d_in[4];
    const float* W_attn    = (const float*)d_in[5];
    const float* b_attn    = (const float*)d_in[6];
    const float* W_v       = (const float*)d_in[7];
    const float* b_v       = (const float*)d_in[8];
    const float* W_out     = (const float*)d_in[9];
    const float* b_out     = (const float*)d_in[10];
    float* out             = (float*)d_out;

    char* base = (char*)d_ws;
    size_t o = 0;
    ushort* value_bf = (ushort*)(base + o); o += (size_t)NQP * 256 * 2;
    ushort* offattn  = (ushort*)(base + o); o += (size_t)NQP * 192 * 2;
    ushort* msda_bf  = (ushort*)(base + o); o += (size_t)NQP * 256 * 2;
    ushort* Bcat     = (ushort*)(base + o); o += 448 * 512 * 2;
    ushort* WoutT    = (ushort*)(base + o); o += 256 * 256 * 2;
    float*  bcat     = (float*)(base + o);  o += 448 * 4;

    prep_weights_kernel<<<(448 * 512 + 65536 + 448 + 255) / 256, 256, 0, stream>>>(
        W_v, W_off, W_attn, W_out, b_v, b_off, b_attn, Bcat, WoutT, bcat);

    fused_front_kernel<<<NQP / 64, 256, 0, stream>>>(
        query, query_pos, Bcat, bcat, value_bf, offattn);

    msda_fused_kernel<<<NQ / 4, 256, 0, stream>>>(value_bf, offattn, refpts, msda_bf);

    gemm_out_kernel<<<dim3(NQP / 128, 4), 256, 0, stream>>>(
        msda_bf, WoutT, b_out, query, out, NQ);
}